// Round 13
// baseline (293.080 us; speedup 1.0000x reference)
//
#include <hip/hip_runtime.h>
#include <hip/hip_bf16.h>
#include <math.h>

typedef __attribute__((ext_vector_type(8))) short short8;
typedef __attribute__((ext_vector_type(16))) float f32x16;

#define NB 4096
#define DIM 128
// sqrt(20 * log2(e)) folded into BOTH operands: acc = 28.8539*dot (log2 units)
#define SQS 5.3715828f

// Raw v_exp_f32 (domain |x|<=28.9 is far from denormal; 1 instr, exact here).
#if __has_builtin(__builtin_amdgcn_exp2f)
#define EX2(x) __builtin_amdgcn_exp2f(x)
#else
#define EX2(x) exp2f(x)
#endif

__device__ inline unsigned short f2bf(float f) {
  unsigned int u = __builtin_bit_cast(unsigned int, f);
  u += 0x7FFFu + ((u >> 16) & 1u);
  return (unsigned short)(u >> 16);
}

__device__ inline float wave_sum(float v) {
#pragma unroll
  for (int off = 32; off >= 1; off >>= 1) v += __shfl_xor(v, off, 64);
  return v;
}

// Parallel int64-vs-int32 links detect (all odd words zero <=> int64) + out=0.
__global__ __launch_bounds__(64) void k_init(const int* links32, int* flag, float* out) {
  int t = threadIdx.x;
  bool ok = (links32[1 + 2 * t] == 0) && (links32[129 + 2 * t] == 0);
  unsigned long long m = __ballot(ok);
  if (t == 0) { *flag = (m == ~0ull) ? 1 : 0; out[0] = 0.0f; }
}

// Pair-per-wave gather + L2-normalize + f32 diag.
// Packs bf16 K-chunked layout Zc[16][4096][8], PRE-SCALED by SQS.
// diagn[p] = 20 * (zi_p . zj_p)  (natural-log units)
__global__ __launch_bounds__(256) void k_normalize(
    const float* __restrict__ emb, const int* __restrict__ links,
    const int* __restrict__ flag,
    unsigned short* __restrict__ Zic, unsigned short* __restrict__ Zjc,
    float* __restrict__ diagn) {
  int wid = threadIdx.x >> 6, lane = threadIdx.x & 63;
  int p = blockIdx.x * 4 + wid;   // pair index 0..4095
  int fl = *flag;
  int idx_i = fl ? links[4 * p + 0] : links[2 * p + 0];
  int idx_j = fl ? links[4 * p + 2] : links[2 * p + 1];
  const float* si = emb + (long long)idx_i * DIM;
  const float* sj = emb + (long long)idx_j * DIM;
  float a0 = si[lane], a1 = si[lane + 64];
  float b0 = sj[lane], b1 = sj[lane + 64];
  float sii = wave_sum(a0 * a0 + a1 * a1);
  float sjj = wave_sum(b0 * b0 + b1 * b1);
  float sij = wave_sum(a0 * b0 + a1 * b1);
  float ni = fmaxf(sqrtf(sii), 1e-12f);
  float nj = fmaxf(sqrtf(sjj), 1e-12f);
  if (lane == 0) diagn[p] = 20.0f * sij / (ni * nj);
  float wi = SQS / ni, wj = SQS / nj;
  size_t o0 = (((size_t)(lane >> 3) + 0) * NB + p) * 8 + (lane & 7);
  size_t o1 = (((size_t)(lane >> 3) + 8) * NB + p) * 8 + (lane & 7);
  Zic[o0] = f2bf(a0 * wi);
  Zic[o1] = f2bf(a1 * wi);
  Zjc[o0] = f2bf(b0 * wj);
  Zjc[o1] = f2bf(b1 * wj);
}

// FUSED pass, 8 waves/block: the 4 Gram chains split across wave pairs.
// waves 0-3 (side A): own xi rows; AB = yj.xi (no skip) + AA = yi.xi (skip) -> ra
// waves 4-7 (side B): own xj rows; BB = yj.xj (skip)  + BA = yi.xj (no skip) -> rb
// Y tiles (yj+yi, 16 KB) staged in LDS once per j-tile by all 512 threads
// (2 loads/thread), double-buffered, issue-early/write-late, 1 barrier/tile.
// Per-wave state ~110 VGPR -> 4 waves/SIMD (2x R12's TLP).
// Layout-agnostic dual per-reg probe (verified R3-R12).
__global__ __launch_bounds__(512, 4) void k_pass(
    const unsigned short* __restrict__ Zic, const unsigned short* __restrict__ Zjc,
    float* __restrict__ rowp_a, float* __restrict__ rowp_b) {
  __shared__ unsigned short yt[2][2][4096];  // [dbuf][0=yj,1=yi][piece*8] 32 KB
  __shared__ float bufr[2][128];
  int tid = threadIdx.x, wid = tid >> 6, lane = tid & 63;
  if (tid < 256) bufr[tid >> 7][tid & 127] = 0.0f;

  int rw = wid & 3;        // row-slot within block
  int side = wid >> 2;     // 0 = A (xi/ra), 1 = B (xj/rb)
  int it0 = blockIdx.x * 128 + rw * 32;   // wave's 32 loss-rows
  int jb = blockIdx.y * 256;              // 8 j-tiles of 32
  int lr = lane & 31;
  int hi = lane >> 5;

  // --- dual per-reg layout probe ---
  short8 pj, pc;
  unsigned short blr = f2bf((float)lr);
#pragma unroll
  for (int e = 0; e < 8; ++e) { pj[e] = (short)blr; pc[e] = (short)0x3D80; }
  f32x16 pr = {}, pn = {};
  pr = __builtin_amdgcn_mfma_f32_32x32x16_bf16(pj, pc, pr, 0, 0, 0);
  pn = __builtin_amdgcn_mfma_f32_32x32x16_bf16(pc, pj, pn, 0, 0, 0);
  unsigned int dmask = 0;
  int imv[4] = {0, 0, 0, 0};
#pragma unroll
  for (int r = 0; r < 16; ++r) {
    int jm = (int)(pr[r] + 0.5f), im = (int)(pn[r] + 0.5f);
    dmask |= (unsigned)(jm == im) << r;
    imv[r >> 2] |= im << ((r & 3) * 8);
  }

  // X fragments for the whole j-loop: 32 rows of this wave's side
  const unsigned short* Xs = side ? Zjc : Zic;
  short8 x[8];
#pragma unroll
  for (int ks = 0; ks < 8; ++ks)
    x[ks] = *reinterpret_cast<const short8*>(
        Xs + ((size_t)(ks * 2 + hi) * NB + (it0 + lr)) * 8);

  float rs[16];
#pragma unroll
  for (int r = 0; r < 16; ++r) rs[r] = 0.0f;

  // prologue: stage tile 0 into buffer 0 (1 piece/side/thread)
  {
    size_t go = ((size_t)(tid >> 5) * NB + (jb + (tid & 31))) * 8;
    *reinterpret_cast<short8*>(&yt[0][0][tid * 8]) =
        *reinterpret_cast<const short8*>(Zjc + go);
    *reinterpret_cast<short8*>(&yt[0][1][tid * 8]) =
        *reinterpret_cast<const short8*>(Zic + go);
  }
  __syncthreads();

  for (int jt = 0; jt < 8; ++jt) {
    int cur = jt & 1, nxt = cur ^ 1;
    int j0 = jb + jt * 32;
    bool dt = (j0 == it0);
    short8 tj, ti;
    if (jt < 7) {  // issue-early: next tile's 2 global loads
      size_t g = ((size_t)(tid >> 5) * NB + (j0 + 32 + (tid & 31))) * 8;
      tj = *reinterpret_cast<const short8*>(Zjc + g);
      ti = *reinterpret_cast<const short8*>(Zic + g);
    }
    f32x16 a0 = {}, a1 = {};   // a0: from yj (AB|BB); a1: from yi (AA|BA)
#pragma unroll
    for (int ks = 0; ks < 8; ++ks) {
      int off = ((ks * 2 + hi) * 32 + lr) * 8;
      short8 yj = *reinterpret_cast<const short8*>(&yt[cur][0][off]);
      short8 yi = *reinterpret_cast<const short8*>(&yt[cur][1][off]);
      a0 = __builtin_amdgcn_mfma_f32_32x32x16_bf16(yj, x[ks], a0, 0, 0, 0);
      a1 = __builtin_amdgcn_mfma_f32_32x32x16_bf16(yi, x[ks], a1, 0, 0, 0);
    }
    if (jt < 7) {  // write-late: staging lands after the MFMAs
      *reinterpret_cast<short8*>(&yt[nxt][0][tid * 8]) = tj;
      *reinterpret_cast<short8*>(&yt[nxt][1][tid * 8]) = ti;
    }
#pragma unroll
    for (int r = 0; r < 16; ++r) {
      float e0 = EX2(a0[r]);   // AB (side A) | BB (side B)
      float e1 = EX2(a1[r]);   // AA (side A) | BA (side B)
      if (dt && ((dmask >> r) & 1u)) {
        if (side) e0 = 0.0f;   // BB diag skip
        else      e1 = 0.0f;   // AA diag skip
      }
      rs[r] += e0 + e1;
    }
    __syncthreads();  // nxt fully staged; cur free for overwrite next iter
  }
  // LDS reduce (2 lanes x 16 regs share each output row; 2 waves per slot)
#pragma unroll
  for (int r = 0; r < 16; ++r) {
    int im = (imv[r >> 2] >> ((r & 3) * 8)) & 0xFF;
    atomicAdd(&bufr[side][rw * 32 + im], rs[r]);
  }
  __syncthreads();
  if (tid < 128)
    rowp_a[(size_t)blockIdx.y * NB + blockIdx.x * 128 + tid] = bufr[0][tid];
  else if (tid < 256)
    rowp_b[(size_t)blockIdx.y * NB + blockIdx.x * 128 + (tid - 128)] = bufr[1][tid - 128];
}

// loss = mean(0.5*(ln sa + ln sb) - diagn)   (e^{+20} scale cancels in ln)
__global__ __launch_bounds__(256) void k_final(
    const float* __restrict__ rowp_a, const float* __restrict__ rowp_b,
    const float* __restrict__ diagn, float* __restrict__ out) {
  int i = blockIdx.x * 256 + threadIdx.x;
  float sa = 0.0f, sb = 0.0f;
#pragma unroll
  for (int y = 0; y < 16; ++y) {
    sa += rowp_a[(size_t)y * NB + i];
    sb += rowp_b[(size_t)y * NB + i];
  }
  float v = 0.5f * (logf(sa) + logf(sb)) - diagn[i];
  v = wave_sum(v);
  __shared__ float sred[4];
  if ((threadIdx.x & 63) == 0) sred[threadIdx.x >> 6] = v;
  __syncthreads();
  if (threadIdx.x == 0)
    atomicAdd(out, (sred[0] + sred[1] + sred[2] + sred[3]) * (1.0f / NB));
}

extern "C" void kernel_launch(void* const* d_in, const int* in_sizes, int n_in,
                              void* d_out, int out_size, void* d_ws, size_t ws_size,
                              hipStream_t stream) {
  const float* emb = (const float*)d_in[0];
  const int* links = (const int*)d_in[1];
  char* ws = (char*)d_ws;
  unsigned short* Zic = (unsigned short*)(ws + 0);       // 1 MB
  unsigned short* Zjc = (unsigned short*)(ws + 1048576); // 1 MB
  float* rowp_a = (float*)(ws + 2097152);                // 16*4096*4 = 256 KB
  float* rowp_b = (float*)(ws + 2359296);                // 256 KB
  float* diagn = (float*)(ws + 2621440);                 // 16 KB
  int* flag = (int*)(ws + 2637824);                      // 4 B
  float* out = (float*)d_out;

  hipLaunchKernelGGL(k_init, dim3(1), dim3(64), 0, stream, links, flag, out);
  hipLaunchKernelGGL(k_normalize, dim3(1024), dim3(256), 0, stream,
                     emb, links, flag, Zic, Zjc, diagn);
  hipLaunchKernelGGL(k_pass, dim3(32, 16), dim3(512), 0, stream,
                     Zic, Zjc, rowp_a, rowp_b);
  hipLaunchKernelGGL(k_final, dim3(16), dim3(256), 0, stream,
                     rowp_a, rowp_b, diagn, out);
}

// Round 14
// 55.913 us; speedup vs baseline: 5.2417x; 5.2417x over previous
//
#include <hip/hip_runtime.h>
#include <hip/hip_bf16.h>
#include <math.h>

typedef __attribute__((ext_vector_type(8))) short short8;
typedef __attribute__((ext_vector_type(16))) float f32x16;

#define NB 4096
#define DIM 128
// sqrt(20 * log2(e)) folded into BOTH operands: acc = 28.8539*dot (log2 units)
#define SQS 5.3715828f

// Raw v_exp_f32 (domain |x|<=28.9 is far from denormal; 1 instr, exact here).
#if __has_builtin(__builtin_amdgcn_exp2f)
#define EX2(x) __builtin_amdgcn_exp2f(x)
#else
#define EX2(x) exp2f(x)
#endif

__device__ inline unsigned short f2bf(float f) {
  unsigned int u = __builtin_bit_cast(unsigned int, f);
  u += 0x7FFFu + ((u >> 16) & 1u);
  return (unsigned short)(u >> 16);
}

__device__ inline float wave_sum(float v) {
#pragma unroll
  for (int off = 32; off >= 1; off >>= 1) v += __shfl_xor(v, off, 64);
  return v;
}

// Parallel int64-vs-int32 links detect (all odd words zero <=> int64) + out=0.
__global__ __launch_bounds__(64) void k_init(const int* links32, int* flag, float* out) {
  int t = threadIdx.x;
  bool ok = (links32[1 + 2 * t] == 0) && (links32[129 + 2 * t] == 0);
  unsigned long long m = __ballot(ok);
  if (t == 0) { *flag = (m == ~0ull) ? 1 : 0; out[0] = 0.0f; }
}

// Pair-per-wave gather + L2-normalize + f32 diag.
// Packs bf16 K-chunked layout Zc[16][4096][8], PRE-SCALED by SQS.
// diagn[p] = 20 * (zi_p . zj_p)  (natural-log units)
__global__ __launch_bounds__(256) void k_normalize(
    const float* __restrict__ emb, const int* __restrict__ links,
    const int* __restrict__ flag,
    unsigned short* __restrict__ Zic, unsigned short* __restrict__ Zjc,
    float* __restrict__ diagn) {
  int wid = threadIdx.x >> 6, lane = threadIdx.x & 63;
  int p = blockIdx.x * 4 + wid;   // pair index 0..4095
  int fl = *flag;
  int idx_i = fl ? links[4 * p + 0] : links[2 * p + 0];
  int idx_j = fl ? links[4 * p + 2] : links[2 * p + 1];
  const float* si = emb + (long long)idx_i * DIM;
  const float* sj = emb + (long long)idx_j * DIM;
  float a0 = si[lane], a1 = si[lane + 64];
  float b0 = sj[lane], b1 = sj[lane + 64];
  float sii = wave_sum(a0 * a0 + a1 * a1);
  float sjj = wave_sum(b0 * b0 + b1 * b1);
  float sij = wave_sum(a0 * b0 + a1 * b1);
  float ni = fmaxf(sqrtf(sii), 1e-12f);
  float nj = fmaxf(sqrtf(sjj), 1e-12f);
  if (lane == 0) diagn[p] = 20.0f * sij / (ni * nj);
  float wi = SQS / ni, wj = SQS / nj;
  size_t o0 = (((size_t)(lane >> 3) + 0) * NB + p) * 8 + (lane & 7);
  size_t o1 = (((size_t)(lane >> 3) + 8) * NB + p) * 8 + (lane & 7);
  Zic[o0] = f2bf(a0 * wi);
  Zic[o1] = f2bf(a1 * wi);
  Zjc[o0] = f2bf(b0 * wj);
  Zjc[o1] = f2bf(b1 * wj);
}

// FUSED pass, 8 waves/block: the 4 Gram chains split across wave pairs.
// waves 0-3 (side A): own xi rows; AB = yj.xi (no skip) + AA = yi.xi (skip) -> ra
// waves 4-7 (side B): own xj rows; BB = yj.xj (skip)  + BA = yi.xj (no skip) -> rb
// Y tiles (yj+yi, 16 KB) staged in LDS once per j-tile by all 512 threads
// (2 loads/thread), double-buffered, issue-early/write-late, 1 barrier/tile.
// NOTE R13 lesson: __launch_bounds__(512,4) forced a 64-VGPR budget -> acc/X
// spill -> 300 MB scratch traffic, 312 us. NO occupancy demand here: the
// natural ~110-130 VGPR allocation gives ~4 waves/EU without spilling.
__global__ __launch_bounds__(512) void k_pass(
    const unsigned short* __restrict__ Zic, const unsigned short* __restrict__ Zjc,
    float* __restrict__ rowp_a, float* __restrict__ rowp_b) {
  __shared__ unsigned short yt[2][2][4096];  // [dbuf][0=yj,1=yi][piece*8] 32 KB
  __shared__ float bufr[2][128];
  int tid = threadIdx.x, wid = tid >> 6, lane = tid & 63;
  if (tid < 256) bufr[tid >> 7][tid & 127] = 0.0f;

  int rw = wid & 3;        // row-slot within block
  int side = wid >> 2;     // 0 = A (xi/ra), 1 = B (xj/rb)
  int it0 = blockIdx.x * 128 + rw * 32;   // wave's 32 loss-rows
  int jb = blockIdx.y * 256;              // 8 j-tiles of 32
  int lr = lane & 31;
  int hi = lane >> 5;

  // --- dual per-reg layout probe (verified R3-R13) ---
  short8 pj, pc;
  unsigned short blr = f2bf((float)lr);
#pragma unroll
  for (int e = 0; e < 8; ++e) { pj[e] = (short)blr; pc[e] = (short)0x3D80; }
  f32x16 pr = {}, pn = {};
  pr = __builtin_amdgcn_mfma_f32_32x32x16_bf16(pj, pc, pr, 0, 0, 0);
  pn = __builtin_amdgcn_mfma_f32_32x32x16_bf16(pc, pj, pn, 0, 0, 0);
  unsigned int dmask = 0;
  int imv[4] = {0, 0, 0, 0};
#pragma unroll
  for (int r = 0; r < 16; ++r) {
    int jm = (int)(pr[r] + 0.5f), im = (int)(pn[r] + 0.5f);
    dmask |= (unsigned)(jm == im) << r;
    imv[r >> 2] |= im << ((r & 3) * 8);
  }

  // X fragments for the whole j-loop: 32 rows of this wave's side
  const unsigned short* Xs = side ? Zjc : Zic;
  short8 x[8];
#pragma unroll
  for (int ks = 0; ks < 8; ++ks)
    x[ks] = *reinterpret_cast<const short8*>(
        Xs + ((size_t)(ks * 2 + hi) * NB + (it0 + lr)) * 8);

  float rs[16];
#pragma unroll
  for (int r = 0; r < 16; ++r) rs[r] = 0.0f;

  // prologue: stage tile 0 into buffer 0 (1 piece/side/thread)
  {
    size_t go = ((size_t)(tid >> 5) * NB + (jb + (tid & 31))) * 8;
    *reinterpret_cast<short8*>(&yt[0][0][tid * 8]) =
        *reinterpret_cast<const short8*>(Zjc + go);
    *reinterpret_cast<short8*>(&yt[0][1][tid * 8]) =
        *reinterpret_cast<const short8*>(Zic + go);
  }
  __syncthreads();

  for (int jt = 0; jt < 8; ++jt) {
    int cur = jt & 1, nxt = cur ^ 1;
    int j0 = jb + jt * 32;
    bool dt = (j0 == it0);
    short8 tj, ti;
    if (jt < 7) {  // issue-early: next tile's 2 global loads
      size_t g = ((size_t)(tid >> 5) * NB + (j0 + 32 + (tid & 31))) * 8;
      tj = *reinterpret_cast<const short8*>(Zjc + g);
      ti = *reinterpret_cast<const short8*>(Zic + g);
    }
    f32x16 a0 = {}, a1 = {};   // a0: from yj (AB|BB); a1: from yi (AA|BA)
#pragma unroll
    for (int ks = 0; ks < 8; ++ks) {
      int off = ((ks * 2 + hi) * 32 + lr) * 8;
      short8 yj = *reinterpret_cast<const short8*>(&yt[cur][0][off]);
      short8 yi = *reinterpret_cast<const short8*>(&yt[cur][1][off]);
      a0 = __builtin_amdgcn_mfma_f32_32x32x16_bf16(yj, x[ks], a0, 0, 0, 0);
      a1 = __builtin_amdgcn_mfma_f32_32x32x16_bf16(yi, x[ks], a1, 0, 0, 0);
    }
    if (jt < 7) {  // write-late: staging lands after the MFMAs
      *reinterpret_cast<short8*>(&yt[nxt][0][tid * 8]) = tj;
      *reinterpret_cast<short8*>(&yt[nxt][1][tid * 8]) = ti;
    }
#pragma unroll
    for (int r = 0; r < 16; ++r) {
      float e0 = EX2(a0[r]);   // AB (side A) | BB (side B)
      float e1 = EX2(a1[r]);   // AA (side A) | BA (side B)
      if (dt && ((dmask >> r) & 1u)) {
        if (side) e0 = 0.0f;   // BB diag skip
        else      e1 = 0.0f;   // AA diag skip
      }
      rs[r] += e0 + e1;
    }
    __syncthreads();  // nxt fully staged; cur free for overwrite next iter
  }
  // LDS reduce (2 lanes x 16 regs share each output row; 2 waves per slot)
#pragma unroll
  for (int r = 0; r < 16; ++r) {
    int im = (imv[r >> 2] >> ((r & 3) * 8)) & 0xFF;
    atomicAdd(&bufr[side][rw * 32 + im], rs[r]);
  }
  __syncthreads();
  if (tid < 128)
    rowp_a[(size_t)blockIdx.y * NB + blockIdx.x * 128 + tid] = bufr[0][tid];
  else if (tid < 256)
    rowp_b[(size_t)blockIdx.y * NB + blockIdx.x * 128 + (tid - 128)] = bufr[1][tid - 128];
}

// loss = mean(0.5*(ln sa + ln sb) - diagn)   (e^{+20} scale cancels in ln)
__global__ __launch_bounds__(256) void k_final(
    const float* __restrict__ rowp_a, const float* __restrict__ rowp_b,
    const float* __restrict__ diagn, float* __restrict__ out) {
  int i = blockIdx.x * 256 + threadIdx.x;
  float sa = 0.0f, sb = 0.0f;
#pragma unroll
  for (int y = 0; y < 16; ++y) {
    sa += rowp_a[(size_t)y * NB + i];
    sb += rowp_b[(size_t)y * NB + i];
  }
  float v = 0.5f * (logf(sa) + logf(sb)) - diagn[i];
  v = wave_sum(v);
  __shared__ float sred[4];
  if ((threadIdx.x & 63) == 0) sred[threadIdx.x >> 6] = v;
  __syncthreads();
  if (threadIdx.x == 0)
    atomicAdd(out, (sred[0] + sred[1] + sred[2] + sred[3]) * (1.0f / NB));
}

extern "C" void kernel_launch(void* const* d_in, const int* in_sizes, int n_in,
                              void* d_out, int out_size, void* d_ws, size_t ws_size,
                              hipStream_t stream) {
  const float* emb = (const float*)d_in[0];
  const int* links = (const int*)d_in[1];
  char* ws = (char*)d_ws;
  unsigned short* Zic = (unsigned short*)(ws + 0);       // 1 MB
  unsigned short* Zjc = (unsigned short*)(ws + 1048576); // 1 MB
  float* rowp_a = (float*)(ws + 2097152);                // 16*4096*4 = 256 KB
  float* rowp_b = (float*)(ws + 2359296);                // 256 KB
  float* diagn = (float*)(ws + 2621440);                 // 16 KB
  int* flag = (int*)(ws + 2637824);                      // 4 B
  float* out = (float*)d_out;

  hipLaunchKernelGGL(k_init, dim3(1), dim3(64), 0, stream, links, flag, out);
  hipLaunchKernelGGL(k_normalize, dim3(1024), dim3(256), 0, stream,
                     emb, links, flag, Zic, Zjc, diagn);
  hipLaunchKernelGGL(k_pass, dim3(32, 16), dim3(512), 0, stream,
                     Zic, Zjc, rowp_a, rowp_b);
  hipLaunchKernelGGL(k_final, dim3(16), dim3(256), 0, stream,
                     rowp_a, rowp_b, diagn, out);
}